// Round 8
// baseline (1457.485 us; speedup 1.0000x reference)
//
#include <hip/hip_runtime.h>

// GCLSDA encoder: ego=concat(U,I); 3x { ego = A@ego; ego += sign(ego)*nhat*0.1; acc+=ego }
// Outputs: final=acc/3, cl=ego_layer1.
// Numerics: SpMM accumulates per (row,dim) sequentially in ascending edge-index
// order with separate _rn mul/add (matches np.add.at); norm uses numpy
// pairwise-sum 8-accumulator pattern. Exact order is LOAD-BEARING: sign(ego)
// amplifies ~1e-7 reorder noise into ~1e-2 errors at near-zero ego elements.
// Do NOT reorder the per-row accumulation.
//
// R8: dim-split k_fused. R7 counters: k_fused = 54% of total, FETCH=866MB of
// which ~764MB is x-gather L2 fill (6.4M x 256B rows, 51.2MB ws vs 32MB
// aggregate L2 -> 47% miss; fill path saturates ~3.9 TB/s). Split each layer
// into TWO dim-half dispatches (d0=0,32): per-dispatch x ws = 25.6MB -> lower
// miss rate -> less fill traffic. cv streamed 2x/layer (+51MB) — net win if
// miss drops below ~40%. Bit-identical: each (row,dim) accumulator is
// independent; edge-walk order and _rn ops untouched; rows 256B-aligned so
// d0=32 stays line-aligned; a row's 8 units are wave-adjacent (cv broadcast).
// R7 (verified): zip gather (one line/edge in k_build). R6: keys-only binning.
// R5: rank recomputed in k_bin phase 3. R3/R4: epilogue fused into spmm;
// layer-0 virtual concat; dead stores dropped.
//
// CSR build: bucket = row>>8 (782 buckets). A1 prep (count+zip) -> scan ->
// A2 bin {key} -> B per-bucket rank-scatter (keys unique ((rl<<24)|e): final
// slot = start[rl] + #{same-row keys < mine}; each cv written ONCE).
// KEY RECOVERY MUST BE LOGICAL SHIFT: (unsigned)key>>24. e = key & 0xFFFFFF.
// Aliasing: keys=bufA (dead before layer-0 ego write), zip=bufB (dead before
// layer-1 ego write); k_build consumes both before any layer runs.

#define USER_NUM 100000
#define N_NODES  200000
#define EMB      64
#define N_EDGES  6400000
#define NBUCK    782        // ceil(200000/256)
#define CAP      9216       // max edges/bucket on LDS fast path (mu=8184, +11 sigma)
#define EPB      16384      // edges per block in A1/A2
#define TB_A     1024       // threads per block in A1/A2

static constexpr size_t BUFA_OFF  = 0;
static constexpr size_t BUFB_OFF  = 51200000;
static constexpr size_t CV_OFF    = 102400000;
static constexpr size_t RS_OFF    = 153600000;
static constexpr size_t SMALL_OFF = 154400016;
static constexpr size_t NRM_OFF   = 155200016;
static constexpr size_t WS_NEED   = 156000016;

// ---- Pass A1: bucket counts + zip write (cols/vals -> int2, coalesced) ----
__global__ __launch_bounds__(TB_A) void k_prep(const int* __restrict__ rows,
                                               const int* __restrict__ cols,
                                               const float* __restrict__ vals,
                                               int* __restrict__ bcnt,
                                               int2* __restrict__ zip) {
    __shared__ int h[NBUCK];
    for (int i = threadIdx.x; i < NBUCK; i += TB_A) h[i] = 0;
    __syncthreads();
    int base = blockIdx.x * EPB;
    int end  = min(base + EPB, N_EDGES);
    for (int e = base + threadIdx.x; e < end; e += TB_A) {
        atomicAdd(&h[rows[e] >> 8], 1);
        zip[e] = make_int2(cols[e], __float_as_int(vals[e]));
    }
    __syncthreads();
    for (int i = threadIdx.x; i < NBUCK; i += TB_A) {
        int c = h[i];
        if (c) atomicAdd(&bcnt[i], c);
    }
}

// ---- scan of 782 bucket counts -> bbase (exclusive), gcur; rs[N]=E ----
__global__ void k_scan782(const int* __restrict__ bcnt, int* __restrict__ bbase,
                          int* __restrict__ gcur, int* __restrict__ rs) {
    __shared__ int s[1024];
    int i = threadIdx.x;
    int v = (i < NBUCK) ? bcnt[i] : 0;
    s[i] = v;
    __syncthreads();
    for (int off = 1; off < 1024; off <<= 1) {
        int t = 0;
        if (i >= off) t = s[i - off];
        __syncthreads();
        s[i] += t;
        __syncthreads();
    }
    if (i < NBUCK) {
        int ex = s[i] - v;
        bbase[i] = ex;
        gcur[i] = ex;
    }
    if (i == 0) rs[N_NODES] = N_EDGES;
}

// ---- Pass A2: bin edge KEYS into bucket regions (keys only). Phase 1: LDS
// histogram. Phase 2: one global reservation per non-empty bucket. Phase 3:
// re-read rows (L2-hot), recompute rank via fresh LDS atomicAdd —
// intra-bucket order is arbitrary (k_build sorts by key). ----
__global__ __launch_bounds__(TB_A) void k_bin(const int* __restrict__ rows,
                                              int* __restrict__ gcur,
                                              int* __restrict__ keys) {
    __shared__ int h[NBUCK];
    __shared__ int gb[NBUCK];
    for (int i = threadIdx.x; i < NBUCK; i += TB_A) h[i] = 0;
    __syncthreads();
    int base = blockIdx.x * EPB;
    int end  = min(base + EPB, N_EDGES);
    for (int e = base + threadIdx.x; e < end; e += TB_A)
        atomicAdd(&h[rows[e] >> 8], 1);
    __syncthreads();
    for (int i = threadIdx.x; i < NBUCK; i += TB_A) {
        int c = h[i];
        gb[i] = c ? atomicAdd(&gcur[i], c) : 0;
        h[i] = 0;
    }
    __syncthreads();
    for (int e = base + threadIdx.x; e < end; e += TB_A) {
        int r = rows[e];
        int b = r >> 8;
        int pos = gb[b] + atomicAdd(&h[b], 1);
        keys[pos] = ((r & 255) << 24) | e;  // e < 2^23, row-local in top byte
    }
}

// ---- Pass B: per-bucket row-grouping + stable (edge-idx) ordering -> cv, rs.
// (col,val) gathered from zip via e = key & 0xFFFFFF: ONE 64B line per edge. ----
__global__ __launch_bounds__(256) void k_build(const int* __restrict__ keys,
                                               const int2* __restrict__ zip,
                                               const int* __restrict__ bcnt,
                                               const int* __restrict__ bbase,
                                               int2* __restrict__ cv,
                                               int* __restrict__ rs) {
    __shared__ int cnt[256];
    __shared__ int start[256];
    __shared__ int cur[256];
    __shared__ int scanbuf[256];
    __shared__ int eKey[CAP];     // grouped keys (fast path)
    int tid = threadIdx.x;
    int b = blockIdx.x;
    int n = bcnt[b];
    int base = bbase[b];
    int rowbase = b << 8;
    cnt[tid] = 0;
    __syncthreads();
    // step 1: per-row-local histogram (LOGICAL shift: rl in [0,255])
    for (int i = tid; i < n; i += 256) {
        unsigned key = (unsigned)keys[base + i];
        atomicAdd(&cnt[key >> 24], 1);
    }
    __syncthreads();
    // exclusive scan of cnt -> start
    int v = cnt[tid];
    scanbuf[tid] = v;
    __syncthreads();
    for (int off = 1; off < 256; off <<= 1) {
        int t = 0;
        if (tid >= off) t = scanbuf[tid - off];
        __syncthreads();
        scanbuf[tid] += t;
        __syncthreads();
    }
    start[tid] = scanbuf[tid] - v;
    {
        int row = rowbase + tid;
        if (row < N_NODES) rs[row] = base + start[tid];
    }
    cur[tid] = 0;
    __syncthreads();
    if (n <= CAP) {
        // step 2: group keys by row into LDS (intra-row order arbitrary here)
        for (int i = tid; i < n; i += 256) {
            int key = keys[base + i];                   // L2-hot re-read
            int rl = (int)((unsigned)key >> 24);
            int p = start[rl] + atomicAdd(&cur[rl], 1);
            eKey[p] = key;
        }
        __syncthreads();
        // step 3: rank = #{same-row keys < mine} -> final slot; write cv ONCE.
        // Keys unique => bijection; same top byte within a row => signed cmp
        // orders by edge idx. (col,val) gathered from zip in one line.
        for (int p = tid; p < n; p += 256) {
            int k = eKey[p];
            int rl = (int)((unsigned)k >> 24);
            int s0 = start[rl];
            int s1 = s0 + cnt[rl];
            int rank = 0;
            int q = s0;
            for (; q + 4 <= s1; q += 4) {
                rank += (eKey[q]     < k);
                rank += (eKey[q + 1] < k);
                rank += (eKey[q + 2] < k);
                rank += (eKey[q + 3] < k);
            }
            for (; q < s1; ++q) rank += (eKey[q] < k);
            int e = k & 0x00FFFFFF;
            cv[base + s0 + rank] = zip[e];
        }
    } else {
        // overflow fallback (statistically unreachable, +11 sigma):
        // scatter keys into cv[].x, per-row insertion sort by key (global,
        // slow but correct), then rewrite each slot from zip via e.
        for (int i = tid; i < n; i += 256) {
            int key = keys[base + i];
            int rl = (int)((unsigned)key >> 24);
            int p = start[rl] + atomicAdd(&cur[rl], 1);
            cv[base + p] = make_int2(key, 0);
        }
        __syncthreads();
        int c = cnt[tid];
        if (c > 1) {
            int s0 = start[tid];
            int s1 = s0 + c;
            for (int i = s0 + 1; i < s1; ++i) {
                int2 kv = cv[base + i];
                int j = i - 1;
                while (j >= s0 && cv[base + j].x > kv.x) {
                    cv[base + j + 1] = cv[base + j];
                    --j;
                }
                cv[base + j + 1] = kv;
            }
        }
        __syncthreads();
        // each slot read exactly once by its own thread, then overwritten
        for (int i = tid; i < n; i += 256) {
            int e = cv[base + i].x & 0x00FFFFFF;
            cv[base + i] = zip[e];
        }
    }
}

// ---- per-row L2 norm of noise, numpy pairwise order (8 accumulators, n=64) ----
__global__ void k_norm(const float* __restrict__ nk, float* __restrict__ nrm) {
    __shared__ float tile[2][64 * 65];
    int wave = threadIdx.x >> 6;
    int lane = threadIdx.x & 63;
    int base = blockIdx.x * 128 + wave * 64;
    for (int rr = 0; rr < 64; ++rr) {
        int row = base + rr;
        float v = 0.f;
        if (row < N_NODES) v = nk[row * EMB + lane];
        tile[wave][rr * 65 + lane] = v;
    }
    __syncthreads();
    int row = base + lane;
    if (row < N_NODES) {
        const float* tp = &tile[wave][lane * 65];
        float rj[8];
        #pragma unroll
        for (int j = 0; j < 8; ++j) {
            float xj = tp[j];
            rj[j] = __fmul_rn(xj, xj);
        }
        #pragma unroll
        for (int i = 8; i < 64; i += 8) {
            #pragma unroll
            for (int j = 0; j < 8; ++j) {
                float xj = tp[i + j];
                rj[j] = __fadd_rn(rj[j], __fmul_rn(xj, xj));
            }
        }
        float s01 = __fadd_rn(rj[0], rj[1]);
        float s23 = __fadd_rn(rj[2], rj[3]);
        float s45 = __fadd_rn(rj[4], rj[5]);
        float s67 = __fadd_rn(rj[6], rj[7]);
        float ss = __fadd_rn(__fadd_rn(s01, s23), __fadd_rn(s45, s67));
        float nv = __fsqrt_rn(ss);
        nv = fmaxf(nv, 1e-12f);
        nrm[row] = nv;
    }
}

// ---- Fused SpMM + epilogue, DIM-SPLIT: each dispatch covers dims
// [d0, d0+32). One thread per (row, 4-dim group) within the half: 8 units
// per row (wave-adjacent -> cv reads broadcast). 3-edge pipelined groups
// (R2 structure). x gather selects {base, rebased col} in-kernel: layer 0
// reads user/item directly (split=100000); layers 1-2 pass split=0, xlo=xhi.
// Epilogue: e4 = y + sign(y)*nk/nrm*0.1;
//   mode0: ego=e4, clF=e4            (accF deferred — mode1 reads clF)
//   mode1: ego=e4, accF=clF+e4
//   mode2: accF=(accF+e4)/3          (ego dead, not written)
__global__ __launch_bounds__(256) void k_fused(const int* __restrict__ rs,
                                               const int2* __restrict__ cv,
                                               const float* __restrict__ xlo,
                                               const float* __restrict__ xhi,
                                               int split,
                                               const float* __restrict__ nk,
                                               const float* __restrict__ nrm,
                                               float* __restrict__ ego,
                                               float* __restrict__ accF,
                                               float* __restrict__ clF,
                                               int mode, int d0) {
    int t = blockIdx.x * blockDim.x + threadIdx.x;
    if (t >= N_NODES * 8) return;
    int r = t >> 3;
    int c = d0 + ((t & 7) << 2);
    int j0 = rs[r], j1 = rs[r + 1];
    float a0 = 0.f, a1 = 0.f, a2 = 0.f, a3 = 0.f;
    if (j0 < j1) {
        const int EMAX = N_EDGES - 1;
        // two-base gather: base and rebased column selected together
        #define XROW(col) (((col) < split ? xlo : xhi) + \
                           ((col) < split ? (col) : (col) - split) * EMB + c)
        int2 c0 = cv[j0];
        int2 c1 = cv[min(j0 + 1, EMAX)];
        int2 c2 = cv[min(j0 + 2, EMAX)];
        int2 n0 = cv[min(j0 + 3, EMAX)];
        int2 n1 = cv[min(j0 + 4, EMAX)];
        int2 n2 = cv[min(j0 + 5, EMAX)];
        int2 m0 = cv[min(j0 + 6, EMAX)];
        int2 m1 = cv[min(j0 + 7, EMAX)];
        int2 m2 = cv[min(j0 + 8, EMAX)];
        float4 x0 = *(const float4*)XROW(c0.x);
        float4 x1 = *(const float4*)XROW(c1.x);
        float4 x2 = *(const float4*)XROW(c2.x);
        for (int j = j0; j < j1; j += 3) {
            // x prefetch for next group (cv loaded 2 iterations ago)
            float4 y0 = *(const float4*)XROW(n0.x);
            float4 y1 = *(const float4*)XROW(n1.x);
            float4 y2 = *(const float4*)XROW(n2.x);
            // accumulate current group (predicate out-of-row edges to v=0;
            // a + (+/-0) is exact, so active-edge order/values unchanged)
            float v0 = __int_as_float(c0.y);
            float v1 = (j + 1 < j1) ? __int_as_float(c1.y) : 0.f;
            float v2 = (j + 2 < j1) ? __int_as_float(c2.y) : 0.f;
            a0 = __fadd_rn(a0, __fmul_rn(v0, x0.x));
            a1 = __fadd_rn(a1, __fmul_rn(v0, x0.y));
            a2 = __fadd_rn(a2, __fmul_rn(v0, x0.z));
            a3 = __fadd_rn(a3, __fmul_rn(v0, x0.w));
            a0 = __fadd_rn(a0, __fmul_rn(v1, x1.x));
            a1 = __fadd_rn(a1, __fmul_rn(v1, x1.y));
            a2 = __fadd_rn(a2, __fmul_rn(v1, x1.z));
            a3 = __fadd_rn(a3, __fmul_rn(v1, x1.w));
            a0 = __fadd_rn(a0, __fmul_rn(v2, x2.x));
            a1 = __fadd_rn(a1, __fmul_rn(v2, x2.y));
            a2 = __fadd_rn(a2, __fmul_rn(v2, x2.z));
            a3 = __fadd_rn(a3, __fmul_rn(v2, x2.w));
            // rotate pipeline
            c0 = n0; c1 = n1; c2 = n2;
            n0 = m0; n1 = m1; n2 = m2;
            x0 = y0; x1 = y1; x2 = y2;
            // streaming cv prefetch, 2 groups ahead of its x-gather
            m0 = cv[min(j + 9,  EMAX)];
            m1 = cv[min(j + 10, EMAX)];
            m2 = cv[min(j + 11, EMAX)];
        }
        #undef XROW
    }
    // ---- fused epilogue (identical math/order to the old k_epi) ----
    int idx = r * EMB + c;
    float4 n4 = *(const float4*)(nk + idx);
    float nv = nrm[r];
    float4 e4;
    {
        float s, q;
        s = (a0 > 0.f) ? 1.f : ((a0 < 0.f) ? -1.f : 0.f);
        q = __fdiv_rn(n4.x, nv);
        e4.x = __fadd_rn(a0, __fmul_rn(__fmul_rn(s, q), 0.1f));
        s = (a1 > 0.f) ? 1.f : ((a1 < 0.f) ? -1.f : 0.f);
        q = __fdiv_rn(n4.y, nv);
        e4.y = __fadd_rn(a1, __fmul_rn(__fmul_rn(s, q), 0.1f));
        s = (a2 > 0.f) ? 1.f : ((a2 < 0.f) ? -1.f : 0.f);
        q = __fdiv_rn(n4.z, nv);
        e4.z = __fadd_rn(a2, __fmul_rn(__fmul_rn(s, q), 0.1f));
        s = (a3 > 0.f) ? 1.f : ((a3 < 0.f) ? -1.f : 0.f);
        q = __fdiv_rn(n4.w, nv);
        e4.w = __fadd_rn(a3, __fmul_rn(__fmul_rn(s, q), 0.1f));
    }
    if (mode == 0) {
        *(float4*)(ego + idx) = e4;
        *(float4*)(clF + idx) = e4;
    } else if (mode == 1) {
        *(float4*)(ego + idx) = e4;
        float4 a = *(const float4*)(clF + idx);   // == acc after layer 0
        a.x = __fadd_rn(a.x, e4.x);
        a.y = __fadd_rn(a.y, e4.y);
        a.z = __fadd_rn(a.z, e4.z);
        a.w = __fadd_rn(a.w, e4.w);
        *(float4*)(accF + idx) = a;
    } else {
        float4 a = *(const float4*)(accF + idx);
        float4 f;
        f.x = __fdiv_rn(__fadd_rn(a.x, e4.x), 3.0f);
        f.y = __fdiv_rn(__fadd_rn(a.y, e4.y), 3.0f);
        f.z = __fdiv_rn(__fadd_rn(a.z, e4.z), 3.0f);
        f.w = __fdiv_rn(__fadd_rn(a.w, e4.w), 3.0f);
        *(float4*)(accF + idx) = f;
    }
}

extern "C" void kernel_launch(void* const* d_in, const int* in_sizes, int n_in,
                              void* d_out, int out_size, void* d_ws, size_t ws_size,
                              hipStream_t stream) {
    if (ws_size < WS_NEED) return;

    const float* user_emb = (const float*)d_in[0];
    const float* item_emb = (const float*)d_in[1];
    const int*   adj_rows = (const int*)d_in[2];
    const int*   adj_cols = (const int*)d_in[3];
    const float* adj_vals = (const float*)d_in[4];
    const float* noise    = (const float*)d_in[5];

    char* ws = (char*)d_ws;
    float* bufA = (float*)(ws + BUFA_OFF);
    float* bufB = (float*)(ws + BUFB_OFF);
    int*   keys = (int*)(ws + BUFA_OFF);    // aliased: dead before bufA first write
    int2*  zip  = (int2*)(ws + BUFB_OFF);   // aliased: dead before bufB first write
    int2*  cv   = (int2*)(ws + CV_OFF);
    int*   rs   = (int*)(ws + RS_OFF);
    int*   bcnt = (int*)(ws + SMALL_OFF);
    int*   bbase= (int*)(ws + SMALL_OFF + 3200);
    int*   gcur = (int*)(ws + SMALL_OFF + 6400);
    float* nrm  = (float*)(ws + NRM_OFF);

    float* accF = (float*)d_out;
    float* clF  = (float*)d_out + (size_t)N_NODES * EMB;

    // ---- CSR build (keys/zip alias bufA/bufB: build completes before any
    //      fused layer writes ego into those buffers; single stream) ----
    hipMemsetAsync(bcnt, 0, NBUCK * sizeof(int), stream);
    const int NBLK = (N_EDGES + EPB - 1) / EPB;  // 391
    k_prep<<<NBLK, TB_A, 0, stream>>>(adj_rows, adj_cols, adj_vals, bcnt, zip);
    k_scan782<<<1, 1024, 0, stream>>>(bcnt, bbase, gcur, rs);
    k_bin<<<NBLK, TB_A, 0, stream>>>(adj_rows, gcur, keys);
    k_build<<<NBUCK, 256, 0, stream>>>(keys, zip, bcnt, bbase, cv, rs);

    // ---- 3 layers: norm(k) then 2 dim-half fused spmm+epilogue(k) ----
    const int T8 = N_NODES * 8;
    for (int k = 0; k < 3; ++k) {
        const float* nkp = noise + (size_t)k * N_NODES * EMB;
        const float* xlo  = (k == 0) ? user_emb : ((k == 1) ? bufA : bufB);
        const float* xhi  = (k == 0) ? item_emb : ((k == 1) ? bufA : bufB);
        int split = (k == 0) ? USER_NUM : 0;
        float* ego_out = (k == 0) ? bufA : bufB;   // k==2 never writes ego
        k_norm<<<(N_NODES + 127) / 128, 128, 0, stream>>>(nkp, nrm);
        k_fused<<<(T8 + 255) / 256, 256, 0, stream>>>(rs, cv, xlo, xhi, split,
                                                      nkp, nrm, ego_out, accF,
                                                      clF, k, 0);
        k_fused<<<(T8 + 255) / 256, 256, 0, stream>>>(rs, cv, xlo, xhi, split,
                                                      nkp, nrm, ego_out, accF,
                                                      clF, k, 32);
    }
}

// Round 9
// 1231.556 us; speedup vs baseline: 1.1835x; 1.1835x over previous
//
#include <hip/hip_runtime.h>

// GCLSDA encoder: ego=concat(U,I); 3x { ego = A@ego; ego += sign(ego)*nhat*0.1; acc+=ego }
// Outputs: final=acc/3, cl=ego_layer1.
// Numerics: SpMM accumulates per (row,dim) sequentially in ascending edge-index
// order with separate _rn mul/add (matches np.add.at); norm uses numpy
// pairwise-sum 8-accumulator pattern. Exact order is LOAD-BEARING: sign(ego)
// amplifies ~1e-7 reorder noise into ~1e-2 errors at near-zero ego elements.
// Do NOT reorder the per-row accumulation or the norm's fold order.
//
// R9: (a) REVERT R8 dim-split — it regressed (1405->1457): random gathers see
// the per-XCD 4MB L2, not the 32MB aggregate, so halving the working set
// didn't cut misses and the doubled cv stream was pure cost. (b) k_norm FUSED
// into k_fused: a row's 16 threads are one 16-lane wave segment; the numpy
// 8-chain pairwise order is a left-fold over even/odd lanes in increasing
// lane order -> 7-step serial __shfl_up(.,2,16) ring (f = fadd(g,q)), lane14
// ends with chains r0..r3, lane15 r4..r7, combine fadd(fadd(f0,f1),
// fadd(f2,f3)) per lane and one cross-shfl -> ss in the reference's exact
// association. Deletes 3 launches + 3x51MB nk re-reads + nrm buffer.
// (c) memset+global atomics removed: k_prep writes per-block partial
// histograms (391x782 ints, aliased into the then-dead cv region); k_scan782
// sums them. Launches/iter: 11 -> 7 (~25us/launch overhead observed).
// R7 (verified): zip gather — k_build FETCH 752->385MB, 274->149us.
// R6: keys-only binning. R5: rank recomputed in k_bin phase 3. R3/R4:
// epilogue fused into spmm; layer-0 virtual concat; dead stores dropped.
//
// CSR build: bucket = row>>8 (782 buckets). A1 prep (partial counts + zip) ->
// scan -> A2 bin {key} -> B per-bucket rank-scatter (keys unique ((rl<<24)|e):
// final slot = start[rl] + #{same-row keys < mine}; each cv written ONCE).
// KEY RECOVERY MUST BE LOGICAL SHIFT: (unsigned)key>>24. e = key & 0xFFFFFF.
// Aliasing timeline: bcnt_part@CV (dead once scanned, before k_build writes
// cv); keys@bufA (dead before layer-0 ego write); zip@bufB (dead before
// layer-1 ego write).

#define USER_NUM 100000
#define N_NODES  200000
#define EMB      64
#define N_EDGES  6400000
#define NBUCK    782        // ceil(200000/256)
#define CAP      9216       // max edges/bucket on LDS fast path (mu=8184, +11 sigma)
#define EPB      16384      // edges per block in A1/A2
#define TB_A     1024       // threads per block in A1/A2
#define NBLK     391        // ceil(N_EDGES/EPB)

static constexpr size_t BUFA_OFF  = 0;
static constexpr size_t BUFB_OFF  = 51200000;
static constexpr size_t CV_OFF    = 102400000;
static constexpr size_t RS_OFF    = 153600000;
static constexpr size_t SMALL_OFF = 154400016;
static constexpr size_t NRM_OFF   = 155200016;   // unused since R9 (norm fused)
static constexpr size_t WS_NEED   = 156000016;

// ---- Pass A1: per-block bucket counts (no atomics/memset) + zip write ----
__global__ __launch_bounds__(TB_A) void k_prep(const int* __restrict__ rows,
                                               const int* __restrict__ cols,
                                               const float* __restrict__ vals,
                                               int* __restrict__ bcnt_part,
                                               int2* __restrict__ zip) {
    __shared__ int h[NBUCK];
    for (int i = threadIdx.x; i < NBUCK; i += TB_A) h[i] = 0;
    __syncthreads();
    int base = blockIdx.x * EPB;
    int end  = min(base + EPB, N_EDGES);
    for (int e = base + threadIdx.x; e < end; e += TB_A) {
        atomicAdd(&h[rows[e] >> 8], 1);
        zip[e] = make_int2(cols[e], __float_as_int(vals[e]));
    }
    __syncthreads();
    for (int i = threadIdx.x; i < NBUCK; i += TB_A)
        bcnt_part[blockIdx.x * NBUCK + i] = h[i];
}

// ---- sum partials + scan 782 -> bcnt, bbase (exclusive), gcur; rs[N]=E ----
__global__ void k_scan782(const int* __restrict__ bcnt_part,
                          int* __restrict__ bcnt, int* __restrict__ bbase,
                          int* __restrict__ gcur, int* __restrict__ rs) {
    __shared__ int s[1024];
    int i = threadIdx.x;
    int v = 0;
    if (i < NBUCK) {
        for (int b = 0; b < NBLK; ++b) v += bcnt_part[b * NBUCK + i];
        bcnt[i] = v;
    }
    s[i] = v;
    __syncthreads();
    for (int off = 1; off < 1024; off <<= 1) {
        int t = 0;
        if (i >= off) t = s[i - off];
        __syncthreads();
        s[i] += t;
        __syncthreads();
    }
    if (i < NBUCK) {
        int ex = s[i] - v;
        bbase[i] = ex;
        gcur[i] = ex;
    }
    if (i == 0) rs[N_NODES] = N_EDGES;
}

// ---- Pass A2: bin edge KEYS into bucket regions (keys only). Phase 1: LDS
// histogram. Phase 2: one global reservation per non-empty bucket. Phase 3:
// re-read rows (L2-hot), recompute rank via fresh LDS atomicAdd —
// intra-bucket order is arbitrary (k_build sorts by key). ----
__global__ __launch_bounds__(TB_A) void k_bin(const int* __restrict__ rows,
                                              int* __restrict__ gcur,
                                              int* __restrict__ keys) {
    __shared__ int h[NBUCK];
    __shared__ int gb[NBUCK];
    for (int i = threadIdx.x; i < NBUCK; i += TB_A) h[i] = 0;
    __syncthreads();
    int base = blockIdx.x * EPB;
    int end  = min(base + EPB, N_EDGES);
    for (int e = base + threadIdx.x; e < end; e += TB_A)
        atomicAdd(&h[rows[e] >> 8], 1);
    __syncthreads();
    for (int i = threadIdx.x; i < NBUCK; i += TB_A) {
        int c = h[i];
        gb[i] = c ? atomicAdd(&gcur[i], c) : 0;
        h[i] = 0;
    }
    __syncthreads();
    for (int e = base + threadIdx.x; e < end; e += TB_A) {
        int r = rows[e];
        int b = r >> 8;
        int pos = gb[b] + atomicAdd(&h[b], 1);
        keys[pos] = ((r & 255) << 24) | e;  // e < 2^23, row-local in top byte
    }
}

// ---- Pass B: per-bucket row-grouping + stable (edge-idx) ordering -> cv, rs.
// (col,val) gathered from zip via e = key & 0xFFFFFF: ONE 64B line per edge. ----
__global__ __launch_bounds__(256) void k_build(const int* __restrict__ keys,
                                               const int2* __restrict__ zip,
                                               const int* __restrict__ bcnt,
                                               const int* __restrict__ bbase,
                                               int2* __restrict__ cv,
                                               int* __restrict__ rs) {
    __shared__ int cnt[256];
    __shared__ int start[256];
    __shared__ int cur[256];
    __shared__ int scanbuf[256];
    __shared__ int eKey[CAP];     // grouped keys (fast path)
    int tid = threadIdx.x;
    int b = blockIdx.x;
    int n = bcnt[b];
    int base = bbase[b];
    int rowbase = b << 8;
    cnt[tid] = 0;
    __syncthreads();
    // step 1: per-row-local histogram (LOGICAL shift: rl in [0,255])
    for (int i = tid; i < n; i += 256) {
        unsigned key = (unsigned)keys[base + i];
        atomicAdd(&cnt[key >> 24], 1);
    }
    __syncthreads();
    // exclusive scan of cnt -> start
    int v = cnt[tid];
    scanbuf[tid] = v;
    __syncthreads();
    for (int off = 1; off < 256; off <<= 1) {
        int t = 0;
        if (tid >= off) t = scanbuf[tid - off];
        __syncthreads();
        scanbuf[tid] += t;
        __syncthreads();
    }
    start[tid] = scanbuf[tid] - v;
    {
        int row = rowbase + tid;
        if (row < N_NODES) rs[row] = base + start[tid];
    }
    cur[tid] = 0;
    __syncthreads();
    if (n <= CAP) {
        // step 2: group keys by row into LDS (intra-row order arbitrary here)
        for (int i = tid; i < n; i += 256) {
            int key = keys[base + i];                   // L2-hot re-read
            int rl = (int)((unsigned)key >> 24);
            int p = start[rl] + atomicAdd(&cur[rl], 1);
            eKey[p] = key;
        }
        __syncthreads();
        // step 3: rank = #{same-row keys < mine} -> final slot; write cv ONCE.
        // Keys unique => bijection; same top byte within a row => signed cmp
        // orders by edge idx. (col,val) gathered from zip in one line.
        for (int p = tid; p < n; p += 256) {
            int k = eKey[p];
            int rl = (int)((unsigned)k >> 24);
            int s0 = start[rl];
            int s1 = s0 + cnt[rl];
            int rank = 0;
            int q = s0;
            for (; q + 4 <= s1; q += 4) {
                rank += (eKey[q]     < k);
                rank += (eKey[q + 1] < k);
                rank += (eKey[q + 2] < k);
                rank += (eKey[q + 3] < k);
            }
            for (; q < s1; ++q) rank += (eKey[q] < k);
            int e = k & 0x00FFFFFF;
            cv[base + s0 + rank] = zip[e];
        }
    } else {
        // overflow fallback (statistically unreachable, +11 sigma):
        // scatter keys into cv[].x, per-row insertion sort by key (global,
        // slow but correct), then rewrite each slot from zip via e.
        for (int i = tid; i < n; i += 256) {
            int key = keys[base + i];
            int rl = (int)((unsigned)key >> 24);
            int p = start[rl] + atomicAdd(&cur[rl], 1);
            cv[base + p] = make_int2(key, 0);
        }
        __syncthreads();
        int c = cnt[tid];
        if (c > 1) {
            int s0 = start[tid];
            int s1 = s0 + c;
            for (int i = s0 + 1; i < s1; ++i) {
                int2 kv = cv[base + i];
                int j = i - 1;
                while (j >= s0 && cv[base + j].x > kv.x) {
                    cv[base + j + 1] = cv[base + j];
                    --j;
                }
                cv[base + j + 1] = kv;
            }
        }
        __syncthreads();
        // each slot read exactly once by its own thread, then overwritten
        for (int i = tid; i < n; i += 256) {
            int e = cv[base + i].x & 0x00FFFFFF;
            cv[base + i] = zip[e];
        }
    }
}

// ---- Fused SpMM + norm + epilogue. One thread per (row, 4-dim group); a
// row's 16 threads form one 16-lane wave segment. Row norm computed in-wave
// (exact numpy pairwise order): lane u holds dims 4u..4u+3; chains rj[0..3]
// are left-folds over even lanes, rj[4..7] over odd lanes, both in increasing
// lane order -> 7-step serial __shfl_up(.,2,16) ring; lane14 ends with
// r0..r3, lane15 with r4..r7; tAB = fadd(fadd(f0,f1),fadd(f2,f3)) gives
// s01+s23 (lane14) and s45+s67 (lane15); ss = fadd(lane14,lane15).
// 3-edge pipelined gather groups (R2 structure). x gather selects {base,
// rebased col} in-kernel: layer 0 reads user/item directly (split=100000);
// layers 1-2 pass split=0, xlo=xhi.
// Epilogue: e4 = y + sign(y)*nk/nv*0.1;
//   mode0: ego=e4, clF=e4            (accF deferred — mode1 reads clF)
//   mode1: ego=e4, accF=clF+e4
//   mode2: accF=(accF+e4)/3          (ego dead, not written)
// NOTE: grid exactly covers N_NODES*16 threads (12500 blocks) — no lane ever
// early-exits, so the shfl ring sees all 16 lanes of every segment.
__global__ __launch_bounds__(256) void k_fused(const int* __restrict__ rs,
                                               const int2* __restrict__ cv,
                                               const float* __restrict__ xlo,
                                               const float* __restrict__ xhi,
                                               int split,
                                               const float* __restrict__ nk,
                                               float* __restrict__ ego,
                                               float* __restrict__ accF,
                                               float* __restrict__ clF,
                                               int mode) {
    int t = blockIdx.x * blockDim.x + threadIdx.x;
    int r = t >> 4;
    int u = t & 15;
    int c = u << 2;
    int idx = t << 2;                       // == r*EMB + c
    // ---- in-wave row norm (exact numpy pairwise order) ----
    float4 n4 = *(const float4*)(nk + idx);
    float q0 = __fmul_rn(n4.x, n4.x);
    float q1 = __fmul_rn(n4.y, n4.y);
    float q2 = __fmul_rn(n4.z, n4.z);
    float q3 = __fmul_rn(n4.w, n4.w);
    float f0 = q0, f1 = q1, f2 = q2, f3 = q3;
    #pragma unroll
    for (int s = 0; s < 7; ++s) {
        float g0 = __shfl_up(f0, 2, 16);
        float g1 = __shfl_up(f1, 2, 16);
        float g2 = __shfl_up(f2, 2, 16);
        float g3 = __shfl_up(f3, 2, 16);
        if (u >= 2) {
            f0 = __fadd_rn(g0, q0);
            f1 = __fadd_rn(g1, q1);
            f2 = __fadd_rn(g2, q2);
            f3 = __fadd_rn(g3, q3);
        }
    }
    float tAB = __fadd_rn(__fadd_rn(f0, f1), __fadd_rn(f2, f3));
    float tlo = __shfl(tAB, 14, 16);        // s01+s23 (chains from even lanes)
    float thi = __shfl(tAB, 15, 16);        // s45+s67 (chains from odd lanes)
    float nv = __fsqrt_rn(__fadd_rn(tlo, thi));
    nv = fmaxf(nv, 1e-12f);
    // ---- SpMM ----
    int j0 = rs[r], j1 = rs[r + 1];
    float a0 = 0.f, a1 = 0.f, a2 = 0.f, a3 = 0.f;
    if (j0 < j1) {
        const int EMAX = N_EDGES - 1;
        // two-base gather: base and rebased column selected together
        #define XROW(col) (((col) < split ? xlo : xhi) + \
                           ((col) < split ? (col) : (col) - split) * EMB + c)
        int2 c0 = cv[j0];
        int2 c1 = cv[min(j0 + 1, EMAX)];
        int2 c2 = cv[min(j0 + 2, EMAX)];
        int2 n0 = cv[min(j0 + 3, EMAX)];
        int2 n1 = cv[min(j0 + 4, EMAX)];
        int2 n2 = cv[min(j0 + 5, EMAX)];
        int2 m0 = cv[min(j0 + 6, EMAX)];
        int2 m1 = cv[min(j0 + 7, EMAX)];
        int2 m2 = cv[min(j0 + 8, EMAX)];
        float4 x0 = *(const float4*)XROW(c0.x);
        float4 x1 = *(const float4*)XROW(c1.x);
        float4 x2 = *(const float4*)XROW(c2.x);
        for (int j = j0; j < j1; j += 3) {
            // x prefetch for next group (cv loaded 2 iterations ago)
            float4 y0 = *(const float4*)XROW(n0.x);
            float4 y1 = *(const float4*)XROW(n1.x);
            float4 y2 = *(const float4*)XROW(n2.x);
            // accumulate current group (predicate out-of-row edges to v=0;
            // a + (+/-0) is exact, so active-edge order/values unchanged)
            float v0 = __int_as_float(c0.y);
            float v1 = (j + 1 < j1) ? __int_as_float(c1.y) : 0.f;
            float v2 = (j + 2 < j1) ? __int_as_float(c2.y) : 0.f;
            a0 = __fadd_rn(a0, __fmul_rn(v0, x0.x));
            a1 = __fadd_rn(a1, __fmul_rn(v0, x0.y));
            a2 = __fadd_rn(a2, __fmul_rn(v0, x0.z));
            a3 = __fadd_rn(a3, __fmul_rn(v0, x0.w));
            a0 = __fadd_rn(a0, __fmul_rn(v1, x1.x));
            a1 = __fadd_rn(a1, __fmul_rn(v1, x1.y));
            a2 = __fadd_rn(a2, __fmul_rn(v1, x1.z));
            a3 = __fadd_rn(a3, __fmul_rn(v1, x1.w));
            a0 = __fadd_rn(a0, __fmul_rn(v2, x2.x));
            a1 = __fadd_rn(a1, __fmul_rn(v2, x2.y));
            a2 = __fadd_rn(a2, __fmul_rn(v2, x2.z));
            a3 = __fadd_rn(a3, __fmul_rn(v2, x2.w));
            // rotate pipeline
            c0 = n0; c1 = n1; c2 = n2;
            n0 = m0; n1 = m1; n2 = m2;
            x0 = y0; x1 = y1; x2 = y2;
            // streaming cv prefetch, 2 groups ahead of its x-gather
            m0 = cv[min(j + 9,  EMAX)];
            m1 = cv[min(j + 10, EMAX)];
            m2 = cv[min(j + 11, EMAX)];
        }
        #undef XROW
    }
    // ---- fused epilogue (identical math/order to the original k_epi) ----
    float4 e4;
    {
        float s, q;
        s = (a0 > 0.f) ? 1.f : ((a0 < 0.f) ? -1.f : 0.f);
        q = __fdiv_rn(n4.x, nv);
        e4.x = __fadd_rn(a0, __fmul_rn(__fmul_rn(s, q), 0.1f));
        s = (a1 > 0.f) ? 1.f : ((a1 < 0.f) ? -1.f : 0.f);
        q = __fdiv_rn(n4.y, nv);
        e4.y = __fadd_rn(a1, __fmul_rn(__fmul_rn(s, q), 0.1f));
        s = (a2 > 0.f) ? 1.f : ((a2 < 0.f) ? -1.f : 0.f);
        q = __fdiv_rn(n4.z, nv);
        e4.z = __fadd_rn(a2, __fmul_rn(__fmul_rn(s, q), 0.1f));
        s = (a3 > 0.f) ? 1.f : ((a3 < 0.f) ? -1.f : 0.f);
        q = __fdiv_rn(n4.w, nv);
        e4.w = __fadd_rn(a3, __fmul_rn(__fmul_rn(s, q), 0.1f));
    }
    if (mode == 0) {
        *(float4*)(ego + idx) = e4;
        *(float4*)(clF + idx) = e4;
    } else if (mode == 1) {
        *(float4*)(ego + idx) = e4;
        float4 a = *(const float4*)(clF + idx);   // == acc after layer 0
        a.x = __fadd_rn(a.x, e4.x);
        a.y = __fadd_rn(a.y, e4.y);
        a.z = __fadd_rn(a.z, e4.z);
        a.w = __fadd_rn(a.w, e4.w);
        *(float4*)(accF + idx) = a;
    } else {
        float4 a = *(const float4*)(accF + idx);
        float4 f;
        f.x = __fdiv_rn(__fadd_rn(a.x, e4.x), 3.0f);
        f.y = __fdiv_rn(__fadd_rn(a.y, e4.y), 3.0f);
        f.z = __fdiv_rn(__fadd_rn(a.z, e4.z), 3.0f);
        f.w = __fdiv_rn(__fadd_rn(a.w, e4.w), 3.0f);
        *(float4*)(accF + idx) = f;
    }
}

extern "C" void kernel_launch(void* const* d_in, const int* in_sizes, int n_in,
                              void* d_out, int out_size, void* d_ws, size_t ws_size,
                              hipStream_t stream) {
    if (ws_size < WS_NEED) return;

    const float* user_emb = (const float*)d_in[0];
    const float* item_emb = (const float*)d_in[1];
    const int*   adj_rows = (const int*)d_in[2];
    const int*   adj_cols = (const int*)d_in[3];
    const float* adj_vals = (const float*)d_in[4];
    const float* noise    = (const float*)d_in[5];

    char* ws = (char*)d_ws;
    float* bufA = (float*)(ws + BUFA_OFF);
    float* bufB = (float*)(ws + BUFB_OFF);
    int*   keys = (int*)(ws + BUFA_OFF);    // aliased: dead before bufA first write
    int2*  zip  = (int2*)(ws + BUFB_OFF);   // aliased: dead before bufB first write
    int*   bcnt_part = (int*)(ws + CV_OFF); // aliased: dead before cv written
    int2*  cv   = (int2*)(ws + CV_OFF);
    int*   rs   = (int*)(ws + RS_OFF);
    int*   bcnt = (int*)(ws + SMALL_OFF);
    int*   bbase= (int*)(ws + SMALL_OFF + 3200);
    int*   gcur = (int*)(ws + SMALL_OFF + 6400);

    float* accF = (float*)d_out;
    float* clF  = (float*)d_out + (size_t)N_NODES * EMB;

    // ---- CSR build (keys/zip/bcnt_part alias bufA/bufB/cv: all consumed
    //      before their aliases are written; single stream) ----
    k_prep<<<NBLK, TB_A, 0, stream>>>(adj_rows, adj_cols, adj_vals, bcnt_part,
                                      zip);
    k_scan782<<<1, 1024, 0, stream>>>(bcnt_part, bcnt, bbase, gcur, rs);
    k_bin<<<NBLK, TB_A, 0, stream>>>(adj_rows, gcur, keys);
    k_build<<<NBUCK, 256, 0, stream>>>(keys, zip, bcnt, bbase, cv, rs);

    // ---- 3 layers: fused norm+spmm+epilogue ----
    const int T16 = N_NODES * 16;
    for (int k = 0; k < 3; ++k) {
        const float* nkp = noise + (size_t)k * N_NODES * EMB;
        const float* xlo  = (k == 0) ? user_emb : ((k == 1) ? bufA : bufB);
        const float* xhi  = (k == 0) ? item_emb : ((k == 1) ? bufA : bufB);
        int split = (k == 0) ? USER_NUM : 0;
        float* ego_out = (k == 0) ? bufA : bufB;   // k==2 never writes ego
        k_fused<<<T16 / 256, 256, 0, stream>>>(rs, cv, xlo, xhi, split,
                                               nkp, ego_out, accF, clF, k);
    }
}